// Round 6
// baseline (1048.409 us; speedup 1.0000x reference)
//
#include <hip/hip_runtime.h>

#define N_ROWS 32768
#define DIM    256
#define NE     256
#define KP     4096
#define NQ     4
#define ND     8388608   // N_ROWS*DIM
#define RESCORE_MARGIN 2e-4f

typedef short short8 __attribute__((ext_vector_type(8)));
typedef float f32x4  __attribute__((ext_vector_type(4)));

__device__ inline float bf2f(unsigned short u) {
  return __uint_as_float(((unsigned)u) << 16);
}
__device__ inline unsigned short f2bf(float f) {
  unsigned u = __float_as_uint(f);
  u += 0x7fffu + ((u >> 16) & 1u);
  return (unsigned short)(u >> 16);
}

// ---------------- stage 0 prep: resid = x, Xn, rnorm, hi/lo split planes ----------------
__global__ __launch_bounds__(256) void prep0_kernel(
    const float* __restrict__ x, float* __restrict__ resid,
    unsigned short* __restrict__ Xn, float* __restrict__ rnorm,
    unsigned short* __restrict__ rH, unsigned short* __restrict__ rL) {
  const int wave = threadIdx.x >> 6, lane = threadIdx.x & 63;
  const int row = blockIdx.x * 4 + wave;
  float4 v = ((const float4*)(x + (size_t)row * DIM))[lane];
  ((float4*)(resid + (size_t)row * DIM))[lane] = v;
  ushort4 h, l;
  h.x = f2bf(v.x); l.x = f2bf(v.x - bf2f(h.x));
  h.y = f2bf(v.y); l.y = f2bf(v.y - bf2f(h.y));
  h.z = f2bf(v.z); l.z = f2bf(v.z - bf2f(h.z));
  h.w = f2bf(v.w); l.w = f2bf(v.w - bf2f(h.w));
  ((ushort4*)(rH + (size_t)row * DIM))[lane] = h;
  ((ushort4*)(rL + (size_t)row * DIM))[lane] = l;
  float ss = v.x * v.x + v.y * v.y + v.z * v.z + v.w * v.w;
#pragma unroll
  for (int m = 1; m < 64; m <<= 1) ss += __shfl_xor(ss, m, 64);
  if (lane == 0) rnorm[row] = ss;
  const float sc = rsqrtf(ss + 1e-12f);
  ushort4 o;
  o.x = f2bf(v.x * sc); o.y = f2bf(v.y * sc);
  o.z = f2bf(v.z * sc); o.w = f2bf(v.w * sc);
  ((ushort4*)(Xn + (size_t)row * DIM))[lane] = o;
}

// ---------------- all codebook row norms (NQ*NE rows), once ----------------
__global__ __launch_bounds__(256) void cbnorm_kernel(
    const float* __restrict__ cb, float* __restrict__ cbn) {
  const int wave = threadIdx.x >> 6, lane = threadIdx.x & 63;
  const int e = blockIdx.x * 4 + wave;  // 0..NQ*NE-1
  float4 v = ((const float4*)(cb + (size_t)e * DIM))[lane];
  float ss = v.x * v.x + v.y * v.y + v.z * v.z + v.w * v.w;
#pragma unroll
  for (int m = 1; m < 64; m <<= 1) ss += __shfl_xor(ss, m, 64);
  if (lane == 0) cbn[e] = ss;
}

// ---------------- codebook hi/lo split (all NQ codebooks), once ----------------
__global__ __launch_bounds__(256) void cbsplit_kernel(
    const float* __restrict__ cb, unsigned short* __restrict__ cbH,
    unsigned short* __restrict__ cbL) {
  const size_t i = (size_t)blockIdx.x * 256 + threadIdx.x;  // 65536 threads
  float4 v = ((const float4*)cb)[i];
  ushort4 h, l;
  h.x = f2bf(v.x); l.x = f2bf(v.x - bf2f(h.x));
  h.y = f2bf(v.y); l.y = f2bf(v.y - bf2f(h.y));
  h.z = f2bf(v.z); l.z = f2bf(v.z - bf2f(h.z));
  h.w = f2bf(v.w); l.w = f2bf(v.w - bf2f(h.w));
  ((ushort4*)cbH)[i] = h;
  ((ushort4*)cbL)[i] = l;
}

// ---------------- per-stage: gather xn[i1] + pos; also zero ssum ----------------
__global__ __launch_bounds__(256) void gather_pos_kernel(
    const unsigned short* __restrict__ Xn, const int* __restrict__ i1,
    const int* __restrict__ i2, unsigned short* __restrict__ Qg,
    float* __restrict__ pos, float* __restrict__ ssum) {
  if (blockIdx.x < 16) ssum[blockIdx.x * 256 + threadIdx.x] = 0.0f;
  const int wave = threadIdx.x >> 6, lane = threadIdx.x & 63;
  const int k = blockIdx.x * 4 + wave;
  const int a = i1[k], b = i2[k];
  ushort4 va = ((const ushort4*)(Xn + (size_t)a * DIM))[lane];
  ushort4 vb = ((const ushort4*)(Xn + (size_t)b * DIM))[lane];
  ((ushort4*)(Qg + (size_t)k * DIM))[lane] = va;
  float d = bf2f(va.x) * bf2f(vb.x) + bf2f(va.y) * bf2f(vb.y) +
            bf2f(va.z) * bf2f(vb.z) + bf2f(va.w) * bf2f(vb.w);
#pragma unroll
  for (int m = 1; m < 64; m <<= 1) d += __shfl_xor(d, m, 64);
  if (lane == 0) pos[k] = d * 10.0f;  // /TEMP
}

// ---------------- per-stage: sim GEMM (MFMA) + sum(exp(logit-10)) ----------------
// grid (16 qtiles of 256, 64 n-chunks of 512 rows), block 256 = 4 waves.
// B fragments read directly from global (L2-hot: each 512-row Xn chunk is
// 256 KB shared by 16 blocks). No LDS, no barriers -> fully pipelined K-loop.
// One b-load = 16 rows x 64 B = 1 KB coalesced.
__global__ __launch_bounds__(256) void sim_lse_kernel(
    const unsigned short* __restrict__ Qg, const unsigned short* __restrict__ Xn,
    float* __restrict__ s_sum) {
  const int tid  = threadIdx.x;
  const int lane = tid & 63;
  const int wave = tid >> 6;
  const int quad = lane >> 4;
  const int l16  = lane & 15;
  const int qbase = blockIdx.x * 256 + wave * 64;
  const int nb0 = blockIdx.y * 512;

  short8 a[4][8];
#pragma unroll
  for (int t = 0; t < 4; ++t) {
    const short8* arow =
        (const short8*)(Qg + (size_t)(qbase + t * 16 + l16) * DIM + quad * 8);
#pragma unroll
    for (int f = 0; f < 8; ++f) a[t][f] = arow[f * 4];
  }
  float s[4][4] = {};
  const float C1 = 14.4269504088896341f;  // 10*log2(e); exp(10d-10)=exp2(d*C1-C1)

  for (int g = 0; g < 32; ++g) {
    const unsigned short* bt = Xn + (size_t)(nb0 + g * 16 + l16) * DIM + quad * 8;
    f32x4 acc[4] = {{0.f, 0.f, 0.f, 0.f}, {0.f, 0.f, 0.f, 0.f},
                    {0.f, 0.f, 0.f, 0.f}, {0.f, 0.f, 0.f, 0.f}};
#pragma unroll
    for (int f = 0; f < 8; ++f) {
      short8 b = *(const short8*)(bt + f * 32);
#pragma unroll
      for (int t = 0; t < 4; ++t)
        acc[t] = __builtin_amdgcn_mfma_f32_16x16x32_bf16(a[t][f], b, acc[t], 0, 0, 0);
    }
#pragma unroll
    for (int t = 0; t < 4; ++t)
#pragma unroll
      for (int i = 0; i < 4; ++i)
        s[t][i] += exp2f(fmaf(acc[t][i], C1, -C1));
  }
#pragma unroll
  for (int m = 1; m < 16; m <<= 1)
#pragma unroll
    for (int t = 0; t < 4; ++t)
#pragma unroll
      for (int i = 0; i < 4; ++i) s[t][i] += __shfl_xor(s[t][i], m, 64);
  if (l16 == 0) {
#pragma unroll
    for (int t = 0; t < 4; ++t)
#pragma unroll
      for (int i = 0; i < 4; ++i)
        atomicAdd(&s_sum[qbase + t * 16 + quad * 4 + i], s[t][i]);
  }
}

// ---------------- per-stage: lse -> outer loss accumulator ----------------
__global__ __launch_bounds__(256) void lse_final_kernel(
    const float* __restrict__ s_sum, const float* __restrict__ pos,
    float* __restrict__ acc, int stage) {
  const int t = threadIdx.x;
  const int k = blockIdx.x * 256 + t;
  float v = 10.0f + __logf(s_sum[k]) - pos[k];
#pragma unroll
  for (int m = 1; m < 64; m <<= 1) v += __shfl_xor(v, m, 64);
  __shared__ float red[4];
  if ((t & 63) == 0) red[t >> 6] = v;
  __syncthreads();
  if (t == 0) atomicAdd(&acc[4 + stage], red[0] + red[1] + red[2] + red[3]);
}

// ---------------- per-stage: MFMA argmin (hi/lo split) + fp32 rescore + update ----------------
// Block owns 32 rows (grid 1024 -> 4 blocks/CU). B fragments read directly from
// the 256 KB split codebook in L2 -> no LDS tile, no staging barriers.
// dot = aL*bH + aH*bL + aH*bH; rank by cbn[e] - 2*dot; rows with top2 gap <
// margin get exact fp32 rescore with the proven (rn - 2d) + cbn formula.
__global__ __launch_bounds__(256) void argmin_update_kernel(
    float* __restrict__ resid, const float* __restrict__ cb,
    const unsigned short* __restrict__ cbH, const unsigned short* __restrict__ cbL,
    const float* __restrict__ cbn, float* __restrict__ rnorm,
    unsigned short* rH, unsigned short* rL,
    float* __restrict__ xq, float* __restrict__ idxf, float* __restrict__ acc,
    unsigned short* __restrict__ Xn, int stage) {
  __shared__ float sV1[4][32];
  __shared__ float sV2[4][32];
  __shared__ int   sIx[4][32];
  __shared__ int   sIdx[32];
  __shared__ int   sFlag[32];
  __shared__ float sred[4];
  const int tid  = threadIdx.x;
  const int lane = tid & 63;
  const int wave = tid >> 6;
  const int quad = lane >> 4;
  const int l16  = lane & 15;
  const int rbase = blockIdx.x * 32;

  f32x4 acc4[2][4];  // [rt][ct] : row rt*16+quad*4+i, e (wave*4+ct)*16+l16
#pragma unroll
  for (int rt = 0; rt < 2; ++rt)
#pragma unroll
    for (int ct = 0; ct < 4; ++ct) acc4[rt][ct] = (f32x4){0.f, 0.f, 0.f, 0.f};

  for (int kf = 0; kf < 8; ++kf) {
    short8 aH[2], aL[2];
#pragma unroll
    for (int rt = 0; rt < 2; ++rt) {
      const size_t off = (size_t)(rbase + rt * 16 + l16) * DIM + kf * 32 + quad * 8;
      aH[rt] = *(const short8*)(rH + off);
      aL[rt] = *(const short8*)(rL + off);
    }
#pragma unroll
    for (int ct = 0; ct < 4; ++ct) {
      const int ctg = wave * 4 + ct;
      const size_t boff = (size_t)(ctg * 16 + l16) * DIM + kf * 32 + quad * 8;
      short8 bH = *(const short8*)(cbH + boff);
      short8 bL = *(const short8*)(cbL + boff);
#pragma unroll
      for (int rt = 0; rt < 2; ++rt) {
        acc4[rt][ct] = __builtin_amdgcn_mfma_f32_16x16x32_bf16(aL[rt], bH, acc4[rt][ct], 0, 0, 0);
        acc4[rt][ct] = __builtin_amdgcn_mfma_f32_16x16x32_bf16(aH[rt], bL, acc4[rt][ct], 0, 0, 0);
        acc4[rt][ct] = __builtin_amdgcn_mfma_f32_16x16x32_bf16(aH[rt], bH, acc4[rt][ct], 0, 0, 0);
      }
    }
  }

  // ---- epilogue: per-row top-2 over this wave's 64 e ----
  float cbe[4];
#pragma unroll
  for (int ct = 0; ct < 4; ++ct) cbe[ct] = cbn[(wave * 4 + ct) * 16 + l16];
#pragma unroll
  for (int rt = 0; rt < 2; ++rt) {
    float b1[4], b2[4]; int e1[4];
#pragma unroll
    for (int i = 0; i < 4; ++i) { b1[i] = 3.4e38f; b2[i] = 3.4e38f; e1[i] = 0; }
#pragma unroll
    for (int ct = 0; ct < 4; ++ct) {
      const int e = (wave * 4 + ct) * 16 + l16;
#pragma unroll
      for (int i = 0; i < 4; ++i) {
        const float v = fmaf(-2.0f, acc4[rt][ct][i], cbe[ct]);
        if (v < b1[i]) { b2[i] = b1[i]; b1[i] = v; e1[i] = e; }
        else if (v < b2[i]) b2[i] = v;
      }
    }
#pragma unroll
    for (int m = 1; m < 16; m <<= 1) {
#pragma unroll
      for (int i = 0; i < 4; ++i) {
        const float o1 = __shfl_xor(b1[i], m, 64);
        const float o2 = __shfl_xor(b2[i], m, 64);
        const int   oe = __shfl_xor(e1[i], m, 64);
        if (o1 < b1[i] || (o1 == b1[i] && oe < e1[i])) {
          b2[i] = fminf(b1[i], o2); b1[i] = o1; e1[i] = oe;
        } else {
          b2[i] = fminf(b2[i], o1);
        }
      }
    }
    if (l16 == 0) {
#pragma unroll
      for (int i = 0; i < 4; ++i) {
        const int r = rt * 16 + quad * 4 + i;
        sV1[wave][r] = b1[i]; sV2[wave][r] = b2[i]; sIx[wave][r] = e1[i];
      }
    }
  }
  __syncthreads();
  if (tid < 32) {
    float v1 = 3.4e38f, v2 = 3.4e38f; int ix = 0;
#pragma unroll
    for (int w = 0; w < 4; ++w) {
      const float a1 = sV1[w][tid], a2 = sV2[w][tid];
      const int ae = sIx[w][tid];
      if (a1 < v1) { v2 = fminf(v1, a2); v1 = a1; ix = ae; }
      else { v2 = fminf(v2, fminf(a1, a2)); }
    }
    sIdx[tid] = ix;
    sFlag[tid] = (v2 - v1 < RESCORE_MARGIN) ? 1 : 0;
  }
  __syncthreads();

  // ---- exact fp32 rescore for flagged rows (rare) ----
  for (int rr = 0; rr < 8; ++rr) {
    const int r = wave * 8 + rr;
    if (sFlag[r]) {
      const int row = rbase + r;
      const float* rrow = resid + (size_t)row * DIM;
      float d[4] = {0.f, 0.f, 0.f, 0.f};
      for (int kb = 0; kb < 64; ++kb) {
        const float4 rv = ((const float4*)rrow)[kb];
#pragma unroll
        for (int j = 0; j < 4; ++j) {
          const float4 cv = ((const float4*)(cb + (size_t)(lane + 64 * j) * DIM))[kb];
          d[j] = fmaf(rv.x, cv.x, d[j]);
          d[j] = fmaf(rv.y, cv.y, d[j]);
          d[j] = fmaf(rv.z, cv.z, d[j]);
          d[j] = fmaf(rv.w, cv.w, d[j]);
        }
      }
      const float rn = rnorm[row];
      float bv = 3.4e38f; int be = 0;
#pragma unroll
      for (int j = 0; j < 4; ++j) {
        const int e = lane + 64 * j;
        const float v = (rn - 2.0f * d[j]) + cbn[e];
        if (v < bv) { bv = v; be = e; }
      }
#pragma unroll
      for (int m = 1; m < 64; m <<= 1) {
        const float vo = __shfl_xor(bv, m, 64);
        const int   eo = __shfl_xor(be, m, 64);
        if (vo < bv || (vo == bv && eo < be)) { bv = vo; be = eo; }
      }
      if (lane == 0) sIdx[r] = be;
    }
  }
  __syncthreads();

  // ---- update phase: wave per row, 8 passes ----
  float msum = 0.0f;
  for (int i = 0; i < 8; ++i) {
    const int rr = i * 4 + wave;
    const int row = rbase + rr;
    const int e = sIdx[rr];
    float4 r4 = ((const float4*)(resid + (size_t)row * DIM))[lane];
    float4 q4 = ((const float4*)(cb + (size_t)e * DIM))[lane];
    float4 nr = {r4.x - q4.x, r4.y - q4.y, r4.z - q4.z, r4.w - q4.w};
    float ss = nr.x * nr.x + nr.y * nr.y + nr.z * nr.z + nr.w * nr.w;
    float4* xp = (float4*)(xq + (size_t)row * DIM) + lane;
    if (stage == 0) {
      *xp = q4;
    } else {
      float4 o = *xp;
      o.x += q4.x; o.y += q4.y; o.z += q4.z; o.w += q4.w;
      *xp = o;
    }
#pragma unroll
    for (int m = 1; m < 64; m <<= 1) ss += __shfl_xor(ss, m, 64);
    if (stage < 3) {
      ((float4*)(resid + (size_t)row * DIM))[lane] = nr;
      ushort4 h, l;
      h.x = f2bf(nr.x); l.x = f2bf(nr.x - bf2f(h.x));
      h.y = f2bf(nr.y); l.y = f2bf(nr.y - bf2f(h.y));
      h.z = f2bf(nr.z); l.z = f2bf(nr.z - bf2f(h.z));
      h.w = f2bf(nr.w); l.w = f2bf(nr.w - bf2f(h.w));
      ((ushort4*)(rH + (size_t)row * DIM))[lane] = h;
      ((ushort4*)(rL + (size_t)row * DIM))[lane] = l;
      const float sc = rsqrtf(ss + 1e-12f);
      ushort4 o;
      o.x = f2bf(nr.x * sc); o.y = f2bf(nr.y * sc);
      o.z = f2bf(nr.z * sc); o.w = f2bf(nr.w * sc);
      ((ushort4*)(Xn + (size_t)row * DIM))[lane] = o;
      if (lane == 0) rnorm[row] = ss;
    }
    if (lane == 0) {
      idxf[(size_t)row * NQ + stage] = (float)e;
      msum += ss;
    }
  }
  if (lane == 0) sred[wave] = msum;
  __syncthreads();
  if (tid == 0) atomicAdd(&acc[0], sred[0] + sred[1] + sred[2] + sred[3]);
}

// ---------------- finalize scalar outputs ----------------
__global__ void finalize_kernel(const float* __restrict__ acc, float* __restrict__ out) {
  const int t = threadIdx.x;
  if (t == 0) out[ND] = acc[0] * (1.25f / (4.0f * (float)ND));
  if (t < 4) out[ND + 1 + t] = acc[4 + t] * (1.0f / (float)KP);
}

extern "C" void kernel_launch(void* const* d_in, const int* in_sizes, int n_in,
                              void* d_out, int out_size, void* d_ws, size_t ws_size,
                              hipStream_t stream) {
  const float* x         = (const float*)d_in[0];
  const float* codebooks = (const float*)d_in[1];
  const int*   i1        = (const int*)d_in[2];
  const int*   i2        = (const int*)d_in[3];
  float* out = (float*)d_out;
  float* out_xq   = out;                 // [N, D]
  float* out_idxf = out + ND + 1 + NQ;   // [N, NQ] as float

  char* w = (char*)d_ws;
  float*          resid = (float*)w;          w += (size_t)N_ROWS * DIM * 4;
  unsigned short* Xn    = (unsigned short*)w; w += (size_t)N_ROWS * DIM * 2;
  unsigned short* rH    = (unsigned short*)w; w += (size_t)N_ROWS * DIM * 2;
  unsigned short* rL    = (unsigned short*)w; w += (size_t)N_ROWS * DIM * 2;
  float*          rnorm = (float*)w;          w += (size_t)N_ROWS * 4;
  unsigned short* Qg    = (unsigned short*)w; w += (size_t)KP * DIM * 2;
  float*          pos   = (float*)w;          w += (size_t)KP * 4;
  float*          ssum  = (float*)w;          w += (size_t)KP * 4;
  float*          cbn   = (float*)w;          w += (size_t)NQ * NE * 4;
  unsigned short* cbH   = (unsigned short*)w; w += (size_t)NQ * NE * DIM * 2;
  unsigned short* cbL   = (unsigned short*)w; w += (size_t)NQ * NE * DIM * 2;
  float*          acc   = (float*)w;          w += 32;  // [0]=sumsq, [4..7]=outer sums

  prep0_kernel<<<8192, 256, 0, stream>>>(x, resid, Xn, rnorm, rH, rL);
  cbnorm_kernel<<<256, 256, 0, stream>>>(codebooks, cbn);
  cbsplit_kernel<<<256, 256, 0, stream>>>(codebooks, cbH, cbL);
  hipMemsetAsync(acc, 0, 32, stream);
  for (int q = 0; q < NQ; ++q) {
    const float* cb = codebooks + (size_t)q * NE * DIM;
    gather_pos_kernel<<<1024, 256, 0, stream>>>(Xn, i1, i2, Qg, pos, ssum);
    sim_lse_kernel<<<dim3(16, 64), 256, 0, stream>>>(Qg, Xn, ssum);
    lse_final_kernel<<<16, 256, 0, stream>>>(ssum, pos, acc, q);
    argmin_update_kernel<<<1024, 256, 0, stream>>>(
        resid, cb, cbH + (size_t)q * NE * DIM, cbL + (size_t)q * NE * DIM,
        cbn + q * NE, rnorm, rH, rL, out_xq, out_idxf, acc, Xn, q);
  }
  finalize_kernel<<<1, 64, 0, stream>>>(acc, out);
}

// Round 7
// 823.162 us; speedup vs baseline: 1.2736x; 1.2736x over previous
//
#include <hip/hip_runtime.h>

#define N_ROWS 32768
#define DIM    256
#define NE     256
#define KP     4096
#define NQ     4
#define ND     8388608   // N_ROWS*DIM
#define RESCORE_MARGIN 2e-4f

typedef short short8 __attribute__((ext_vector_type(8)));
typedef unsigned short ushort8v __attribute__((ext_vector_type(8)));
typedef float f32x4  __attribute__((ext_vector_type(4)));

__device__ inline float bf2f(unsigned short u) {
  return __uint_as_float(((unsigned)u) << 16);
}
__device__ inline unsigned short f2bf(float f) {
  unsigned u = __float_as_uint(f);
  u += 0x7fffu + ((u >> 16) & 1u);
  return (unsigned short)(u >> 16);
}

// Fragment-major packed layout (16B chunks): chunk (tile*8+f)*64 + quad*16 + l16
// holds row tile*16+l16, dims [f*32+quad*8, +8). Equivalently for row r, dim
// chunk j (=k/8): index ((r>>4)*8 + (j>>2))*64 + ((j&3)<<4) + (r&15).
__device__ inline size_t chunkIdx(int row, int j) {
  return (size_t)(((row >> 4) * 8 + (j >> 2)) * 64 + ((j & 3) << 4) + (row & 15));
}

// ---------------- stage 0 prep: resid = x, packed Xn/rH/rL, rnorm ----------------
__global__ __launch_bounds__(256) void prep0_kernel(
    const float* __restrict__ x, float* __restrict__ resid,
    unsigned short* __restrict__ Xnp, float* __restrict__ rnorm,
    unsigned short* __restrict__ rHp, unsigned short* __restrict__ rLp) {
  const int tid = threadIdx.x, wave = tid >> 6, lane = tid & 63;
  const int half = lane >> 5, j = lane & 31;
  const int row = blockIdx.x * 8 + wave * 2 + half;  // grid 4096
  const float4* xr = (const float4*)(x + (size_t)row * DIM + j * 8);
  float4 v0 = xr[0], v1 = xr[1];
  float4* rr = (float4*)(resid + (size_t)row * DIM + j * 8);
  rr[0] = v0; rr[1] = v1;
  float vv[8] = {v0.x, v0.y, v0.z, v0.w, v1.x, v1.y, v1.z, v1.w};
  float ss = 0.f;
#pragma unroll
  for (int i = 0; i < 8; ++i) ss += vv[i] * vv[i];
#pragma unroll
  for (int m = 1; m < 32; m <<= 1) ss += __shfl_xor(ss, m, 64);
  if (j == 0) rnorm[row] = ss;
  const float sc = rsqrtf(ss + 1e-12f);
  ushort8v h, l, xn;
#pragma unroll
  for (int i = 0; i < 8; ++i) {
    h[i] = f2bf(vv[i]); l[i] = f2bf(vv[i] - bf2f(h[i])); xn[i] = f2bf(vv[i] * sc);
  }
  const size_t c = chunkIdx(row, j) * 8;
  *(ushort8v*)(rHp + c) = h;
  *(ushort8v*)(rLp + c) = l;
  *(ushort8v*)(Xnp + c) = xn;
}

// ---------------- all codebook row norms (NQ*NE rows), once ----------------
__global__ __launch_bounds__(256) void cbnorm_kernel(
    const float* __restrict__ cb, float* __restrict__ cbn) {
  const int wave = threadIdx.x >> 6, lane = threadIdx.x & 63;
  const int e = blockIdx.x * 4 + wave;  // 0..NQ*NE-1
  float4 v = ((const float4*)(cb + (size_t)e * DIM))[lane];
  float ss = v.x * v.x + v.y * v.y + v.z * v.z + v.w * v.w;
#pragma unroll
  for (int m = 1; m < 64; m <<= 1) ss += __shfl_xor(ss, m, 64);
  if (lane == 0) cbn[e] = ss;
}

// ---------------- codebook hi/lo split, packed, all stages, once ----------------
__global__ __launch_bounds__(256) void cbsplit_kernel(
    const float* __restrict__ cb, unsigned short* __restrict__ cbHp,
    unsigned short* __restrict__ cbLp) {
  const int p = blockIdx.x * 256 + threadIdx.x;  // grid 128 -> 32768 chunks
  const int stage = p >> 13, ps = p & 8191;
  const int l16 = ps & 15, quad = (ps >> 4) & 3, kf = (ps >> 6) & 7, et = ps >> 9;
  const int e = et * 16 + l16, k0 = kf * 32 + quad * 8;
  const float* src = cb + ((size_t)(stage * NE + e)) * DIM + k0;
  float4 v0 = ((const float4*)src)[0], v1 = ((const float4*)src)[1];
  float vv[8] = {v0.x, v0.y, v0.z, v0.w, v1.x, v1.y, v1.z, v1.w};
  ushort8v h, l;
#pragma unroll
  for (int i = 0; i < 8; ++i) {
    h[i] = f2bf(vv[i]); l[i] = f2bf(vv[i] - bf2f(h[i]));
  }
  *(ushort8v*)(cbHp + (size_t)p * 8) = h;
  *(ushort8v*)(cbLp + (size_t)p * 8) = l;
}

// ---------------- per-stage: gather xn[i1] (packed Qg) + pos; zero ssum ----------------
__global__ __launch_bounds__(256) void gather_pos_kernel(
    const unsigned short* __restrict__ Xnp, const int* __restrict__ i1,
    const int* __restrict__ i2, unsigned short* __restrict__ Qgp,
    float* __restrict__ pos, float* __restrict__ ssum) {
  if (blockIdx.x < 16) ssum[blockIdx.x * 256 + threadIdx.x] = 0.0f;
  const int wave = threadIdx.x >> 6, lane = threadIdx.x & 63;
  const int k = blockIdx.x * 4 + wave;
  const int a = i1[k], b = i2[k];
  const int j2 = lane >> 1, off = (lane & 1) * 4;
  ushort4 va = *(const ushort4*)(Xnp + chunkIdx(a, j2) * 8 + off);
  ushort4 vb = *(const ushort4*)(Xnp + chunkIdx(b, j2) * 8 + off);
  *(ushort4*)(Qgp + chunkIdx(k, j2) * 8 + off) = va;
  float d = bf2f(va.x) * bf2f(vb.x) + bf2f(va.y) * bf2f(vb.y) +
            bf2f(va.z) * bf2f(vb.z) + bf2f(va.w) * bf2f(vb.w);
#pragma unroll
  for (int m = 1; m < 64; m <<= 1) d += __shfl_xor(d, m, 64);
  if (lane == 0) pos[k] = d * 10.0f;  // /TEMP
}

// ---------------- per-stage: sim GEMM (MFMA) + sum(exp(logit-10)) ----------------
// grid (16 qtiles of 256, 64 n-chunks of 512), block 256 = 4 waves.
// All operands in fragment-packed layout: every load is 1KB coalesced. No LDS.
// launch_bounds(256,2): VGPR cap 256 so the 128-reg A-array stays resident.
__global__ __launch_bounds__(256, 2) void sim_lse_kernel(
    const unsigned short* __restrict__ Qgp, const unsigned short* __restrict__ Xnp,
    float* __restrict__ s_sum) {
  const int tid  = threadIdx.x;
  const int lane = tid & 63;
  const int wave = tid >> 6;
  const int quad = lane >> 4;
  const int l16  = lane & 15;
  const int qt0  = blockIdx.x * 16 + wave * 4;
  const int qbase = blockIdx.x * 256 + wave * 64;

  short8 a[4][8];
#pragma unroll
  for (int t = 0; t < 4; ++t)
#pragma unroll
    for (int f = 0; f < 8; ++f)
      a[t][f] = *(const short8*)(Qgp + ((size_t)(((qt0 + t) * 8 + f) * 64 + lane)) * 8);

  float s[4][4] = {};
  const float C1 = 14.4269504088896341f;  // 10*log2(e); exp(10d-10)=exp2(d*C1-C1)

  for (int g = 0; g < 32; ++g) {
    const int ntile = blockIdx.y * 32 + g;
    short8 b[8];
#pragma unroll
    for (int f = 0; f < 8; ++f)
      b[f] = *(const short8*)(Xnp + ((size_t)((ntile * 8 + f) * 64 + lane)) * 8);
    f32x4 acc[4] = {{0.f, 0.f, 0.f, 0.f}, {0.f, 0.f, 0.f, 0.f},
                    {0.f, 0.f, 0.f, 0.f}, {0.f, 0.f, 0.f, 0.f}};
#pragma unroll
    for (int f = 0; f < 8; ++f)
#pragma unroll
      for (int t = 0; t < 4; ++t)
        acc[t] = __builtin_amdgcn_mfma_f32_16x16x32_bf16(a[t][f], b[f], acc[t], 0, 0, 0);
#pragma unroll
    for (int t = 0; t < 4; ++t)
#pragma unroll
      for (int i = 0; i < 4; ++i)
        s[t][i] += exp2f(fmaf(acc[t][i], C1, -C1));
  }
#pragma unroll
  for (int m = 1; m < 16; m <<= 1)
#pragma unroll
    for (int t = 0; t < 4; ++t)
#pragma unroll
      for (int i = 0; i < 4; ++i) s[t][i] += __shfl_xor(s[t][i], m, 64);
  if (l16 == 0) {
#pragma unroll
    for (int t = 0; t < 4; ++t)
#pragma unroll
      for (int i = 0; i < 4; ++i)
        atomicAdd(&s_sum[qbase + t * 16 + quad * 4 + i], s[t][i]);
  }
}

// ---------------- per-stage: lse -> outer loss accumulator ----------------
__global__ __launch_bounds__(256) void lse_final_kernel(
    const float* __restrict__ s_sum, const float* __restrict__ pos,
    float* __restrict__ acc, int stage) {
  const int t = threadIdx.x;
  const int k = blockIdx.x * 256 + t;
  float v = 10.0f + __logf(s_sum[k]) - pos[k];
#pragma unroll
  for (int m = 1; m < 64; m <<= 1) v += __shfl_xor(v, m, 64);
  __shared__ float red[4];
  if ((t & 63) == 0) red[t >> 6] = v;
  __syncthreads();
  if (t == 0) atomicAdd(&acc[4 + stage], red[0] + red[1] + red[2] + red[3]);
}

// ---------------- per-stage: MFMA argmin (hi/lo) + fp32 rescore + update ----------------
// 32 rows/block (grid 1024). Packed operands -> coalesced loads, no LDS tile.
__global__ __launch_bounds__(256) void argmin_update_kernel(
    float* __restrict__ resid, const float* __restrict__ cb,
    const unsigned short* __restrict__ cbHp, const unsigned short* __restrict__ cbLp,
    const float* __restrict__ cbn, float* __restrict__ rnorm,
    unsigned short* rHp, unsigned short* rLp,
    float* __restrict__ xq, float* __restrict__ idxf, float* __restrict__ acc,
    unsigned short* __restrict__ Xnp, int stage) {
  __shared__ float sV1[4][32];
  __shared__ float sV2[4][32];
  __shared__ int   sIx[4][32];
  __shared__ int   sIdx[32];
  __shared__ int   sFlag[32];
  __shared__ float sred[4];
  const int tid  = threadIdx.x;
  const int lane = tid & 63;
  const int wave = tid >> 6;
  const int quad = lane >> 4;
  const int l16  = lane & 15;
  const int rbase = blockIdx.x * 32;
  const int t0 = blockIdx.x * 2;

  f32x4 acc4[2][4];  // [rt][ct] : row rt*16+quad*4+i, e (wave*4+ct)*16+l16
#pragma unroll
  for (int rt = 0; rt < 2; ++rt)
#pragma unroll
    for (int ct = 0; ct < 4; ++ct) acc4[rt][ct] = (f32x4){0.f, 0.f, 0.f, 0.f};

  for (int kf = 0; kf < 8; ++kf) {
    short8 aH[2], aL[2];
#pragma unroll
    for (int rt = 0; rt < 2; ++rt) {
      const size_t off = ((size_t)(((t0 + rt) * 8 + kf) * 64 + lane)) * 8;
      aH[rt] = *(const short8*)(rHp + off);
      aL[rt] = *(const short8*)(rLp + off);
    }
#pragma unroll
    for (int ct = 0; ct < 4; ++ct) {
      const int etile = wave * 4 + ct;
      const size_t boff = ((size_t)((etile * 8 + kf) * 64 + lane)) * 8;
      short8 bH = *(const short8*)(cbHp + boff);
      short8 bL = *(const short8*)(cbLp + boff);
#pragma unroll
      for (int rt = 0; rt < 2; ++rt) {
        acc4[rt][ct] = __builtin_amdgcn_mfma_f32_16x16x32_bf16(aL[rt], bH, acc4[rt][ct], 0, 0, 0);
        acc4[rt][ct] = __builtin_amdgcn_mfma_f32_16x16x32_bf16(aH[rt], bL, acc4[rt][ct], 0, 0, 0);
        acc4[rt][ct] = __builtin_amdgcn_mfma_f32_16x16x32_bf16(aH[rt], bH, acc4[rt][ct], 0, 0, 0);
      }
    }
  }

  // ---- epilogue: per-row top-2 over this wave's 64 e ----
  float cbe[4];
#pragma unroll
  for (int ct = 0; ct < 4; ++ct) cbe[ct] = cbn[(wave * 4 + ct) * 16 + l16];
#pragma unroll
  for (int rt = 0; rt < 2; ++rt) {
    float b1[4], b2[4]; int e1[4];
#pragma unroll
    for (int i = 0; i < 4; ++i) { b1[i] = 3.4e38f; b2[i] = 3.4e38f; e1[i] = 0; }
#pragma unroll
    for (int ct = 0; ct < 4; ++ct) {
      const int e = (wave * 4 + ct) * 16 + l16;
#pragma unroll
      for (int i = 0; i < 4; ++i) {
        const float v = fmaf(-2.0f, acc4[rt][ct][i], cbe[ct]);
        if (v < b1[i]) { b2[i] = b1[i]; b1[i] = v; e1[i] = e; }
        else if (v < b2[i]) b2[i] = v;
      }
    }
#pragma unroll
    for (int m = 1; m < 16; m <<= 1) {
#pragma unroll
      for (int i = 0; i < 4; ++i) {
        const float o1 = __shfl_xor(b1[i], m, 64);
        const float o2 = __shfl_xor(b2[i], m, 64);
        const int   oe = __shfl_xor(e1[i], m, 64);
        if (o1 < b1[i] || (o1 == b1[i] && oe < e1[i])) {
          b2[i] = fminf(b1[i], o2); b1[i] = o1; e1[i] = oe;
        } else {
          b2[i] = fminf(b2[i], o1);
        }
      }
    }
    if (l16 == 0) {
#pragma unroll
      for (int i = 0; i < 4; ++i) {
        const int r = rt * 16 + quad * 4 + i;
        sV1[wave][r] = b1[i]; sV2[wave][r] = b2[i]; sIx[wave][r] = e1[i];
      }
    }
  }
  __syncthreads();
  if (tid < 32) {
    float v1 = 3.4e38f, v2 = 3.4e38f; int ix = 0;
#pragma unroll
    for (int w = 0; w < 4; ++w) {
      const float a1 = sV1[w][tid], a2 = sV2[w][tid];
      const int ae = sIx[w][tid];
      if (a1 < v1) { v2 = fminf(v1, a2); v1 = a1; ix = ae; }
      else { v2 = fminf(v2, fminf(a1, a2)); }
    }
    sIdx[tid] = ix;
    sFlag[tid] = (v2 - v1 < RESCORE_MARGIN) ? 1 : 0;
  }
  __syncthreads();

  // ---- exact fp32 rescore for flagged rows (rare) ----
  for (int rr = 0; rr < 8; ++rr) {
    const int r = wave * 8 + rr;
    if (sFlag[r]) {
      const int row = rbase + r;
      const float* rrow = resid + (size_t)row * DIM;
      float d[4] = {0.f, 0.f, 0.f, 0.f};
      for (int kb = 0; kb < 64; ++kb) {
        const float4 rv = ((const float4*)rrow)[kb];
#pragma unroll
        for (int j = 0; j < 4; ++j) {
          const float4 cv = ((const float4*)(cb + (size_t)(lane + 64 * j) * DIM))[kb];
          d[j] = fmaf(rv.x, cv.x, d[j]);
          d[j] = fmaf(rv.y, cv.y, d[j]);
          d[j] = fmaf(rv.z, cv.z, d[j]);
          d[j] = fmaf(rv.w, cv.w, d[j]);
        }
      }
      const float rn = rnorm[row];
      float bv = 3.4e38f; int be = 0;
#pragma unroll
      for (int j = 0; j < 4; ++j) {
        const int e = lane + 64 * j;
        const float v = (rn - 2.0f * d[j]) + cbn[e];
        if (v < bv) { bv = v; be = e; }
      }
#pragma unroll
      for (int m = 1; m < 64; m <<= 1) {
        const float vo = __shfl_xor(bv, m, 64);
        const int   eo = __shfl_xor(be, m, 64);
        if (vo < bv || (vo == bv && eo < be)) { bv = vo; be = eo; }
      }
      if (lane == 0) sIdx[r] = be;
    }
  }
  __syncthreads();

  // ---- update phase: 2 rows/wave x 4 passes (packed stores are natural 16B) ----
  const int half = lane >> 5, j = lane & 31;
  float msum = 0.0f;
  for (int i = 0; i < 4; ++i) {
    const int rr = i * 8 + wave * 2 + half;
    const int row = rbase + rr;
    const int e = sIdx[rr];
    const float4* rp = (const float4*)(resid + (size_t)row * DIM + j * 8);
    float4 r0 = rp[0], r1 = rp[1];
    const float4* qp = (const float4*)(cb + (size_t)e * DIM + j * 8);
    float4 q0 = qp[0], q1 = qp[1];
    float nr[8] = {r0.x - q0.x, r0.y - q0.y, r0.z - q0.z, r0.w - q0.w,
                   r1.x - q1.x, r1.y - q1.y, r1.z - q1.z, r1.w - q1.w};
    float ss = 0.f;
#pragma unroll
    for (int u = 0; u < 8; ++u) ss += nr[u] * nr[u];
    float4* xp = (float4*)(xq + (size_t)row * DIM + j * 8);
    if (stage == 0) {
      xp[0] = q0; xp[1] = q1;
    } else {
      float4 o0 = xp[0], o1 = xp[1];
      o0.x += q0.x; o0.y += q0.y; o0.z += q0.z; o0.w += q0.w;
      o1.x += q1.x; o1.y += q1.y; o1.z += q1.z; o1.w += q1.w;
      xp[0] = o0; xp[1] = o1;
    }
#pragma unroll
    for (int m = 1; m < 32; m <<= 1) ss += __shfl_xor(ss, m, 64);
    if (stage < 3) {
      float4* rw = (float4*)(resid + (size_t)row * DIM + j * 8);
      rw[0] = (float4){nr[0], nr[1], nr[2], nr[3]};
      rw[1] = (float4){nr[4], nr[5], nr[6], nr[7]};
      const float sc = rsqrtf(ss + 1e-12f);
      ushort8v h, l, xn;
#pragma unroll
      for (int u = 0; u < 8; ++u) {
        h[u] = f2bf(nr[u]); l[u] = f2bf(nr[u] - bf2f(h[u])); xn[u] = f2bf(nr[u] * sc);
      }
      const size_t c = chunkIdx(row, j) * 8;
      *(ushort8v*)(rHp + c) = h;
      *(ushort8v*)(rLp + c) = l;
      *(ushort8v*)(Xnp + c) = xn;
      if (j == 0) rnorm[row] = ss;
    }
    if (j == 0) {
      idxf[(size_t)row * NQ + stage] = (float)e;
      msum += ss;
    }
  }
  msum += __shfl_xor(msum, 32, 64);
  if (lane == 0) sred[wave] = msum;
  __syncthreads();
  if (tid == 0) atomicAdd(&acc[0], sred[0] + sred[1] + sred[2] + sred[3]);
}

// ---------------- finalize scalar outputs ----------------
__global__ void finalize_kernel(const float* __restrict__ acc, float* __restrict__ out) {
  const int t = threadIdx.x;
  if (t == 0) out[ND] = acc[0] * (1.25f / (4.0f * (float)ND));
  if (t < 4) out[ND + 1 + t] = acc[4 + t] * (1.0f / (float)KP);
}

extern "C" void kernel_launch(void* const* d_in, const int* in_sizes, int n_in,
                              void* d_out, int out_size, void* d_ws, size_t ws_size,
                              hipStream_t stream) {
  const float* x         = (const float*)d_in[0];
  const float* codebooks = (const float*)d_in[1];
  const int*   i1        = (const int*)d_in[2];
  const int*   i2        = (const int*)d_in[3];
  float* out = (float*)d_out;
  float* out_xq   = out;                 // [N, D]
  float* out_idxf = out + ND + 1 + NQ;   // [N, NQ] as float

  char* w = (char*)d_ws;
  float*          resid = (float*)w;          w += (size_t)N_ROWS * DIM * 4;
  unsigned short* Xnp   = (unsigned short*)w; w += (size_t)N_ROWS * DIM * 2;
  unsigned short* rHp   = (unsigned short*)w; w += (size_t)N_ROWS * DIM * 2;
  unsigned short* rLp   = (unsigned short*)w; w += (size_t)N_ROWS * DIM * 2;
  float*          rnorm = (float*)w;          w += (size_t)N_ROWS * 4;
  unsigned short* Qgp   = (unsigned short*)w; w += (size_t)KP * DIM * 2;
  float*          pos   = (float*)w;          w += (size_t)KP * 4;
  float*          ssum  = (float*)w;          w += (size_t)KP * 4;
  float*          cbn   = (float*)w;          w += (size_t)NQ * NE * 4;
  unsigned short* cbHp  = (unsigned short*)w; w += (size_t)NQ * NE * DIM * 2;
  unsigned short* cbLp  = (unsigned short*)w; w += (size_t)NQ * NE * DIM * 2;
  float*          acc   = (float*)w;          w += 32;  // [0]=sumsq, [4..7]=outer sums

  prep0_kernel<<<4096, 256, 0, stream>>>(x, resid, Xnp, rnorm, rHp, rLp);
  cbnorm_kernel<<<256, 256, 0, stream>>>(codebooks, cbn);
  cbsplit_kernel<<<128, 256, 0, stream>>>(codebooks, cbHp, cbLp);
  hipMemsetAsync(acc, 0, 32, stream);
  for (int q = 0; q < NQ; ++q) {
    const float* cb = codebooks + (size_t)q * NE * DIM;
    gather_pos_kernel<<<1024, 256, 0, stream>>>(Xnp, i1, i2, Qgp, pos, ssum);
    sim_lse_kernel<<<dim3(16, 64), 256, 0, stream>>>(Qgp, Xnp, ssum);
    lse_final_kernel<<<16, 256, 0, stream>>>(ssum, pos, acc, q);
    argmin_update_kernel<<<1024, 256, 0, stream>>>(
        resid, cb, cbHp + (size_t)q * NE * DIM, cbLp + (size_t)q * NE * DIM,
        cbn + q * NE, rnorm, rHp, rLp, out_xq, out_idxf, acc, Xnp, q);
  }
  finalize_kernel<<<1, 64, 0, stream>>>(acc, out);
}

// Round 8
// 716.885 us; speedup vs baseline: 1.4625x; 1.1482x over previous
//
#include <hip/hip_runtime.h>

#define N_ROWS 32768
#define DIM    256
#define NE     256
#define KP     4096
#define NQ     4
#define ND     8388608   // N_ROWS*DIM
#define RESCORE_MARGIN 2e-4f

typedef short short8 __attribute__((ext_vector_type(8)));
typedef unsigned short ushort8v __attribute__((ext_vector_type(8)));
typedef float f32x4  __attribute__((ext_vector_type(4)));

__device__ inline float bf2f(unsigned short u) {
  return __uint_as_float(((unsigned)u) << 16);
}
__device__ inline unsigned short f2bf(float f) {
  unsigned u = __float_as_uint(f);
  u += 0x7fffu + ((u >> 16) & 1u);
  return (unsigned short)(u >> 16);
}

// Fragment-major packed layout (16B chunks): chunk (tile*8+f)*64 + quad*16 + l16
// holds row tile*16+l16, dims [f*32+quad*8, +8). For row r, dim chunk j (=k/8):
// index ((r>>4)*8 + (j>>2))*64 + ((j&3)<<4) + (r&15).
__device__ inline size_t chunkIdx(int row, int j) {
  return (size_t)(((row >> 4) * 8 + (j >> 2)) * 64 + ((j & 3) << 4) + (row & 15));
}

// ---------------- stage 0 prep: resid = x, packed Xn/rH/rL, rnorm ----------------
__global__ __launch_bounds__(256) void prep0_kernel(
    const float* __restrict__ x, float* __restrict__ resid,
    unsigned short* __restrict__ Xnp, float* __restrict__ rnorm,
    unsigned short* __restrict__ rHp, unsigned short* __restrict__ rLp) {
  const int tid = threadIdx.x, wave = tid >> 6, lane = tid & 63;
  const int half = lane >> 5, j = lane & 31;
  const int row = blockIdx.x * 8 + wave * 2 + half;  // grid 4096
  const float4* xr = (const float4*)(x + (size_t)row * DIM + j * 8);
  float4 v0 = xr[0], v1 = xr[1];
  float4* rr = (float4*)(resid + (size_t)row * DIM + j * 8);
  rr[0] = v0; rr[1] = v1;
  float vv[8] = {v0.x, v0.y, v0.z, v0.w, v1.x, v1.y, v1.z, v1.w};
  float ss = 0.f;
#pragma unroll
  for (int i = 0; i < 8; ++i) ss += vv[i] * vv[i];
#pragma unroll
  for (int m = 1; m < 32; m <<= 1) ss += __shfl_xor(ss, m, 64);
  if (j == 0) rnorm[row] = ss;
  const float sc = rsqrtf(ss + 1e-12f);
  ushort8v h, l, xn;
#pragma unroll
  for (int i = 0; i < 8; ++i) {
    h[i] = f2bf(vv[i]); l[i] = f2bf(vv[i] - bf2f(h[i])); xn[i] = f2bf(vv[i] * sc);
  }
  const size_t c = chunkIdx(row, j) * 8;
  *(ushort8v*)(rHp + c) = h;
  *(ushort8v*)(rLp + c) = l;
  *(ushort8v*)(Xnp + c) = xn;
}

// ---------------- all codebook row norms (NQ*NE rows), once ----------------
__global__ __launch_bounds__(256) void cbnorm_kernel(
    const float* __restrict__ cb, float* __restrict__ cbn) {
  const int wave = threadIdx.x >> 6, lane = threadIdx.x & 63;
  const int e = blockIdx.x * 4 + wave;  // 0..NQ*NE-1
  float4 v = ((const float4*)(cb + (size_t)e * DIM))[lane];
  float ss = v.x * v.x + v.y * v.y + v.z * v.z + v.w * v.w;
#pragma unroll
  for (int m = 1; m < 64; m <<= 1) ss += __shfl_xor(ss, m, 64);
  if (lane == 0) cbn[e] = ss;
}

// ---------------- codebook hi/lo split, packed, all stages, once ----------------
__global__ __launch_bounds__(256) void cbsplit_kernel(
    const float* __restrict__ cb, unsigned short* __restrict__ cbHp,
    unsigned short* __restrict__ cbLp) {
  const int p = blockIdx.x * 256 + threadIdx.x;  // grid 128 -> 32768 chunks
  const int stage = p >> 13, ps = p & 8191;
  const int l16 = ps & 15, quad = (ps >> 4) & 3, kf = (ps >> 6) & 7, et = ps >> 9;
  const int e = et * 16 + l16, k0 = kf * 32 + quad * 8;
  const float* src = cb + ((size_t)(stage * NE + e)) * DIM + k0;
  float4 v0 = ((const float4*)src)[0], v1 = ((const float4*)src)[1];
  float vv[8] = {v0.x, v0.y, v0.z, v0.w, v1.x, v1.y, v1.z, v1.w};
  ushort8v h, l;
#pragma unroll
  for (int i = 0; i < 8; ++i) {
    h[i] = f2bf(vv[i]); l[i] = f2bf(vv[i] - bf2f(h[i]));
  }
  *(ushort8v*)(cbHp + (size_t)p * 8) = h;
  *(ushort8v*)(cbLp + (size_t)p * 8) = l;
}

// ---------------- per-stage: gather xn[i1] (packed Qg) + pos; zero ssum ----------------
__global__ __launch_bounds__(256) void gather_pos_kernel(
    const unsigned short* __restrict__ Xnp, const int* __restrict__ i1,
    const int* __restrict__ i2, unsigned short* __restrict__ Qgp,
    float* __restrict__ pos, float* __restrict__ ssum) {
  if (blockIdx.x < 16) ssum[blockIdx.x * 256 + threadIdx.x] = 0.0f;
  const int wave = threadIdx.x >> 6, lane = threadIdx.x & 63;
  const int k = blockIdx.x * 4 + wave;
  const int a = i1[k], b = i2[k];
  const int j2 = lane >> 1, off = (lane & 1) * 4;
  ushort4 va = *(const ushort4*)(Xnp + chunkIdx(a, j2) * 8 + off);
  ushort4 vb = *(const ushort4*)(Xnp + chunkIdx(b, j2) * 8 + off);
  *(ushort4*)(Qgp + chunkIdx(k, j2) * 8 + off) = va;
  float d = bf2f(va.x) * bf2f(vb.x) + bf2f(va.y) * bf2f(vb.y) +
            bf2f(va.z) * bf2f(vb.z) + bf2f(va.w) * bf2f(vb.w);
#pragma unroll
  for (int m = 1; m < 64; m <<= 1) d += __shfl_xor(d, m, 64);
  if (lane == 0) pos[k] = d * 10.0f;  // /TEMP
}

// ---------------- per-stage: sim GEMM (MFMA) + sum(exp(logit-10)) ----------------
// grid (32 qtiles of 128, 64 n-chunks of 512), block 256 = 4 waves.
// 2 A-tiles/wave resident (64 VGPR), B register ping-pong double-buffer:
// fine-grained vmcnt waits (never 0), one full group of latency covered.
__global__ __launch_bounds__(256, 2) void sim_lse_kernel(
    const unsigned short* __restrict__ Qgp, const unsigned short* __restrict__ Xnp,
    float* __restrict__ s_sum) {
  const int tid  = threadIdx.x;
  const int lane = tid & 63;
  const int wave = tid >> 6;
  const int quad = lane >> 4;
  const int l16  = lane & 15;
  const int qt0  = blockIdx.x * 8 + wave * 2;
  const int qbase = blockIdx.x * 128 + wave * 32;

  short8 a[2][8];
#pragma unroll
  for (int t = 0; t < 2; ++t)
#pragma unroll
    for (int f = 0; f < 8; ++f)
      a[t][f] = *(const short8*)(Qgp + ((size_t)(((qt0 + t) * 8 + f) * 64 + lane)) * 8);

  float s[2][4] = {};
  const float C1 = 14.4269504088896341f;  // 10*log2(e); exp(10d-10)=exp2(d*C1-C1)
  const unsigned short* bgp = Xnp + (size_t)(blockIdx.y * 32) * 4096 + lane * 8;

  auto loadB = [&](int g, short8 (&bb)[8]) {
    const unsigned short* p = bgp + (size_t)g * 4096;
#pragma unroll
    for (int f = 0; f < 8; ++f) bb[f] = *(const short8*)(p + f * 512);
  };
  auto compute = [&](short8 (&bb)[8]) {
    f32x4 acc[2] = {{0.f, 0.f, 0.f, 0.f}, {0.f, 0.f, 0.f, 0.f}};
#pragma unroll
    for (int f = 0; f < 8; ++f)
#pragma unroll
      for (int t = 0; t < 2; ++t)
        acc[t] = __builtin_amdgcn_mfma_f32_16x16x32_bf16(a[t][f], bb[f], acc[t], 0, 0, 0);
#pragma unroll
    for (int t = 0; t < 2; ++t)
#pragma unroll
      for (int i = 0; i < 4; ++i)
        s[t][i] += exp2f(fmaf(acc[t][i], C1, -C1));
  };

  short8 b0[8], b1[8];
  loadB(0, b0);
  for (int g = 0; g < 32; g += 2) {
    loadB(g + 1, b1);
    compute(b0);
    if (g + 2 < 32) loadB(g + 2, b0);
    compute(b1);
  }
#pragma unroll
  for (int m = 1; m < 16; m <<= 1)
#pragma unroll
    for (int t = 0; t < 2; ++t)
#pragma unroll
      for (int i = 0; i < 4; ++i) s[t][i] += __shfl_xor(s[t][i], m, 64);
  if (l16 == 0) {
#pragma unroll
    for (int t = 0; t < 2; ++t)
#pragma unroll
      for (int i = 0; i < 4; ++i)
        atomicAdd(&s_sum[qbase + t * 16 + quad * 4 + i], s[t][i]);
  }
}

// ---------------- per-stage: lse -> outer loss accumulator ----------------
__global__ __launch_bounds__(256) void lse_final_kernel(
    const float* __restrict__ s_sum, const float* __restrict__ pos,
    float* __restrict__ acc, int stage) {
  const int t = threadIdx.x;
  const int k = blockIdx.x * 256 + t;
  float v = 10.0f + __logf(s_sum[k]) - pos[k];
#pragma unroll
  for (int m = 1; m < 64; m <<= 1) v += __shfl_xor(v, m, 64);
  __shared__ float red[4];
  if ((t & 63) == 0) red[t >> 6] = v;
  __syncthreads();
  if (t == 0) atomicAdd(&acc[4 + stage], red[0] + red[1] + red[2] + red[3]);
}

// ---------------- per-stage: MFMA argmin (hi/lo) + fp32 rescore + update ----------------
// 32 rows/block (grid 1024). Packed operands, kf-loop register ping-pong.
__global__ __launch_bounds__(256, 2) void argmin_update_kernel(
    float* __restrict__ resid, const float* __restrict__ cb,
    const unsigned short* __restrict__ cbHp, const unsigned short* __restrict__ cbLp,
    const float* __restrict__ cbn, float* __restrict__ rnorm,
    unsigned short* rHp, unsigned short* rLp,
    float* __restrict__ xq, float* __restrict__ idxf, float* __restrict__ acc,
    unsigned short* __restrict__ Xnp, int stage) {
  __shared__ float sV1[4][32];
  __shared__ float sV2[4][32];
  __shared__ int   sIx[4][32];
  __shared__ int   sIdx[32];
  __shared__ int   sFlag[32];
  __shared__ float sred[4];
  const int tid  = threadIdx.x;
  const int lane = tid & 63;
  const int wave = tid >> 6;
  const int quad = lane >> 4;
  const int l16  = lane & 15;
  const int rbase = blockIdx.x * 32;
  const int t0 = blockIdx.x * 2;

  f32x4 acc4[2][4];  // [rt][ct] : row rt*16+quad*4+i, e (wave*4+ct)*16+l16
#pragma unroll
  for (int rt = 0; rt < 2; ++rt)
#pragma unroll
    for (int ct = 0; ct < 4; ++ct) acc4[rt][ct] = (f32x4){0.f, 0.f, 0.f, 0.f};

  auto loadA = [&](int kf, short8 (&aH)[2], short8 (&aL)[2]) {
#pragma unroll
    for (int rt = 0; rt < 2; ++rt) {
      const size_t off = ((size_t)(((t0 + rt) * 8 + kf) * 64 + lane)) * 8;
      aH[rt] = *(const short8*)(rHp + off);
      aL[rt] = *(const short8*)(rLp + off);
    }
  };
  auto loadBc = [&](int kf, short8 (&bH)[4], short8 (&bL)[4]) {
#pragma unroll
    for (int ct = 0; ct < 4; ++ct) {
      const size_t boff = ((size_t)(((wave * 4 + ct) * 8 + kf) * 64 + lane)) * 8;
      bH[ct] = *(const short8*)(cbHp + boff);
      bL[ct] = *(const short8*)(cbLp + boff);
    }
  };
  auto computeK = [&](short8 (&aH)[2], short8 (&aL)[2], short8 (&bH)[4],
                      short8 (&bL)[4]) {
#pragma unroll
    for (int ct = 0; ct < 4; ++ct)
#pragma unroll
      for (int rt = 0; rt < 2; ++rt) {
        acc4[rt][ct] = __builtin_amdgcn_mfma_f32_16x16x32_bf16(aL[rt], bH[ct], acc4[rt][ct], 0, 0, 0);
        acc4[rt][ct] = __builtin_amdgcn_mfma_f32_16x16x32_bf16(aH[rt], bL[ct], acc4[rt][ct], 0, 0, 0);
        acc4[rt][ct] = __builtin_amdgcn_mfma_f32_16x16x32_bf16(aH[rt], bH[ct], acc4[rt][ct], 0, 0, 0);
      }
  };

  short8 aH0[2], aL0[2], bH0[4], bL0[4], aH1[2], aL1[2], bH1[4], bL1[4];
  loadA(0, aH0, aL0); loadBc(0, bH0, bL0);
  for (int kf = 0; kf < 8; kf += 2) {
    loadA(kf + 1, aH1, aL1); loadBc(kf + 1, bH1, bL1);
    computeK(aH0, aL0, bH0, bL0);
    if (kf + 2 < 8) { loadA(kf + 2, aH0, aL0); loadBc(kf + 2, bH0, bL0); }
    computeK(aH1, aL1, bH1, bL1);
  }

  // ---- epilogue: per-row top-2 over this wave's 64 e ----
  float cbe[4];
#pragma unroll
  for (int ct = 0; ct < 4; ++ct) cbe[ct] = cbn[(wave * 4 + ct) * 16 + l16];
#pragma unroll
  for (int rt = 0; rt < 2; ++rt) {
    float b1[4], b2[4]; int e1[4];
#pragma unroll
    for (int i = 0; i < 4; ++i) { b1[i] = 3.4e38f; b2[i] = 3.4e38f; e1[i] = 0; }
#pragma unroll
    for (int ct = 0; ct < 4; ++ct) {
      const int e = (wave * 4 + ct) * 16 + l16;
#pragma unroll
      for (int i = 0; i < 4; ++i) {
        const float v = fmaf(-2.0f, acc4[rt][ct][i], cbe[ct]);
        if (v < b1[i]) { b2[i] = b1[i]; b1[i] = v; e1[i] = e; }
        else if (v < b2[i]) b2[i] = v;
      }
    }
#pragma unroll
    for (int m = 1; m < 16; m <<= 1) {
#pragma unroll
      for (int i = 0; i < 4; ++i) {
        const float o1 = __shfl_xor(b1[i], m, 64);
        const float o2 = __shfl_xor(b2[i], m, 64);
        const int   oe = __shfl_xor(e1[i], m, 64);
        if (o1 < b1[i] || (o1 == b1[i] && oe < e1[i])) {
          b2[i] = fminf(b1[i], o2); b1[i] = o1; e1[i] = oe;
        } else {
          b2[i] = fminf(b2[i], o1);
        }
      }
    }
    if (l16 == 0) {
#pragma unroll
      for (int i = 0; i < 4; ++i) {
        const int r = rt * 16 + quad * 4 + i;
        sV1[wave][r] = b1[i]; sV2[wave][r] = b2[i]; sIx[wave][r] = e1[i];
      }
    }
  }
  __syncthreads();
  if (tid < 32) {
    float v1 = 3.4e38f, v2 = 3.4e38f; int ix = 0;
#pragma unroll
    for (int w = 0; w < 4; ++w) {
      const float a1 = sV1[w][tid], a2 = sV2[w][tid];
      const int ae = sIx[w][tid];
      if (a1 < v1) { v2 = fminf(v1, a2); v1 = a1; ix = ae; }
      else { v2 = fminf(v2, fminf(a1, a2)); }
    }
    sIdx[tid] = ix;
    sFlag[tid] = (v2 - v1 < RESCORE_MARGIN) ? 1 : 0;
  }
  __syncthreads();

  // ---- exact fp32 rescore for flagged rows (rare) ----
  for (int rr = 0; rr < 8; ++rr) {
    const int r = wave * 8 + rr;
    if (sFlag[r]) {
      const int row = rbase + r;
      const float* rrow = resid + (size_t)row * DIM;
      float d[4] = {0.f, 0.f, 0.f, 0.f};
      for (int kb = 0; kb < 64; ++kb) {
        const float4 rv = ((const float4*)rrow)[kb];
#pragma unroll
        for (int j = 0; j < 4; ++j) {
          const float4 cv = ((const float4*)(cb + (size_t)(lane + 64 * j) * DIM))[kb];
          d[j] = fmaf(rv.x, cv.x, d[j]);
          d[j] = fmaf(rv.y, cv.y, d[j]);
          d[j] = fmaf(rv.z, cv.z, d[j]);
          d[j] = fmaf(rv.w, cv.w, d[j]);
        }
      }
      const float rn = rnorm[row];
      float bv = 3.4e38f; int be = 0;
#pragma unroll
      for (int j = 0; j < 4; ++j) {
        const int e = lane + 64 * j;
        const float v = (rn - 2.0f * d[j]) + cbn[e];
        if (v < bv) { bv = v; be = e; }
      }
#pragma unroll
      for (int m = 1; m < 64; m <<= 1) {
        const float vo = __shfl_xor(bv, m, 64);
        const int   eo = __shfl_xor(be, m, 64);
        if (vo < bv || (vo == bv && eo < be)) { bv = vo; be = eo; }
      }
      if (lane == 0) sIdx[r] = be;
    }
  }
  __syncthreads();

  // ---- update phase: 2 rows/wave x 4 passes (packed stores are natural 16B) ----
  const int half = lane >> 5, j = lane & 31;
  float msum = 0.0f;
  for (int i = 0; i < 4; ++i) {
    const int rr = i * 8 + wave * 2 + half;
    const int row = rbase + rr;
    const int e = sIdx[rr];
    const float4* rp = (const float4*)(resid + (size_t)row * DIM + j * 8);
    float4 r0 = rp[0], r1 = rp[1];
    const float4* qp = (const float4*)(cb + (size_t)e * DIM + j * 8);
    float4 q0 = qp[0], q1 = qp[1];
    float nr[8] = {r0.x - q0.x, r0.y - q0.y, r0.z - q0.z, r0.w - q0.w,
                   r1.x - q1.x, r1.y - q1.y, r1.z - q1.z, r1.w - q1.w};
    float ss = 0.f;
#pragma unroll
    for (int u = 0; u < 8; ++u) ss += nr[u] * nr[u];
    float4* xp = (float4*)(xq + (size_t)row * DIM + j * 8);
    if (stage == 0) {
      xp[0] = q0; xp[1] = q1;
    } else {
      float4 o0 = xp[0], o1 = xp[1];
      o0.x += q0.x; o0.y += q0.y; o0.z += q0.z; o0.w += q0.w;
      o1.x += q1.x; o1.y += q1.y; o1.z += q1.z; o1.w += q1.w;
      xp[0] = o0; xp[1] = o1;
    }
#pragma unroll
    for (int m = 1; m < 32; m <<= 1) ss += __shfl_xor(ss, m, 64);
    if (stage < 3) {
      float4* rw = (float4*)(resid + (size_t)row * DIM + j * 8);
      rw[0] = (float4){nr[0], nr[1], nr[2], nr[3]};
      rw[1] = (float4){nr[4], nr[5], nr[6], nr[7]};
      const float sc = rsqrtf(ss + 1e-12f);
      ushort8v h, l, xn;
#pragma unroll
      for (int u = 0; u < 8; ++u) {
        h[u] = f2bf(nr[u]); l[u] = f2bf(nr[u] - bf2f(h[u])); xn[u] = f2bf(nr[u] * sc);
      }
      const size_t c = chunkIdx(row, j) * 8;
      *(ushort8v*)(rHp + c) = h;
      *(ushort8v*)(rLp + c) = l;
      *(ushort8v*)(Xnp + c) = xn;
      if (j == 0) rnorm[row] = ss;
    }
    if (j == 0) {
      idxf[(size_t)row * NQ + stage] = (float)e;
      msum += ss;
    }
  }
  msum += __shfl_xor(msum, 32, 64);
  if (lane == 0) sred[wave] = msum;
  __syncthreads();
  if (tid == 0) atomicAdd(&acc[0], sred[0] + sred[1] + sred[2] + sred[3]);
}

// ---------------- finalize scalar outputs ----------------
__global__ void finalize_kernel(const float* __restrict__ acc, float* __restrict__ out) {
  const int t = threadIdx.x;
  if (t == 0) out[ND] = acc[0] * (1.25f / (4.0f * (float)ND));
  if (t < 4) out[ND + 1 + t] = acc[4 + t] * (1.0f / (float)KP);
}

extern "C" void kernel_launch(void* const* d_in, const int* in_sizes, int n_in,
                              void* d_out, int out_size, void* d_ws, size_t ws_size,
                              hipStream_t stream) {
  const float* x         = (const float*)d_in[0];
  const float* codebooks = (const float*)d_in[1];
  const int*   i1        = (const int*)d_in[2];
  const int*   i2        = (const int*)d_in[3];
  float* out = (float*)d_out;
  float* out_xq   = out;                 // [N, D]
  float* out_idxf = out + ND + 1 + NQ;   // [N, NQ] as float

  char* w = (char*)d_ws;
  float*          resid = (float*)w;          w += (size_t)N_ROWS * DIM * 4;
  unsigned short* Xnp   = (unsigned short*)w; w += (size_t)N_ROWS * DIM * 2;
  unsigned short* rHp   = (unsigned short*)w; w += (size_t)N_ROWS * DIM * 2;
  unsigned short* rLp   = (unsigned short*)w; w += (size_t)N_ROWS * DIM * 2;
  float*          rnorm = (float*)w;          w += (size_t)N_ROWS * 4;
  unsigned short* Qgp   = (unsigned short*)w; w += (size_t)KP * DIM * 2;
  float*          pos   = (float*)w;          w += (size_t)KP * 4;
  float*          ssum  = (float*)w;          w += (size_t)KP * 4;
  float*          cbn   = (float*)w;          w += (size_t)NQ * NE * 4;
  unsigned short* cbHp  = (unsigned short*)w; w += (size_t)NQ * NE * DIM * 2;
  unsigned short* cbLp  = (unsigned short*)w; w += (size_t)NQ * NE * DIM * 2;
  float*          acc   = (float*)w;          w += 32;  // [0]=sumsq, [4..7]=outer sums

  prep0_kernel<<<4096, 256, 0, stream>>>(x, resid, Xnp, rnorm, rHp, rLp);
  cbnorm_kernel<<<256, 256, 0, stream>>>(codebooks, cbn);
  cbsplit_kernel<<<128, 256, 0, stream>>>(codebooks, cbHp, cbLp);
  hipMemsetAsync(acc, 0, 32, stream);
  for (int q = 0; q < NQ; ++q) {
    const float* cb = codebooks + (size_t)q * NE * DIM;
    gather_pos_kernel<<<1024, 256, 0, stream>>>(Xnp, i1, i2, Qgp, pos, ssum);
    sim_lse_kernel<<<dim3(32, 64), 256, 0, stream>>>(Qgp, Xnp, ssum);
    lse_final_kernel<<<16, 256, 0, stream>>>(ssum, pos, acc, q);
    argmin_update_kernel<<<1024, 256, 0, stream>>>(
        resid, cb, cbHp + (size_t)q * NE * DIM, cbLp + (size_t)q * NE * DIM,
        cbn + q * NE, rnorm, rHp, rLp, out_xq, out_idxf, acc, Xnp, q);
  }
  finalize_kernel<<<1, 64, 0, stream>>>(acc, out);
}